// Round 5
// baseline (718.911 us; speedup 1.0000x reference)
//
#include <hip/hip_runtime.h>
#include <math.h>
#include <stdint.h>

#define NLEVELS 16
#define TSIZE   (1u << 19)
#define HMASK   (TSIZE - 1u)
#define P1 2654435761u
#define P2 805459861u

typedef float v2f __attribute__((ext_vector_type(2)));
typedef float v4f __attribute__((ext_vector_type(4)));

struct LevelParams { float cell[NLEVELS]; };

__device__ __forceinline__ uint32_t bf16_rne(float f) {
    uint32_t b = __float_as_uint(f);
    return (b + 0x7FFFu + ((b >> 16) & 1u)) >> 16;   // round-to-nearest-even
}

// ---------------------------------------------------------------------------
// Phase 0: f32 tables -> packed bf16x2 (4 B/entry) in ws (rebuilt every call).
__global__ __launch_bounds__(256) void convert_tables_kernel(
    const v2f* __restrict__ tables, uint32_t* __restrict__ tab16,
    unsigned int nEntries)
{
    unsigned int i = blockIdx.x * 256u + threadIdx.x;
    if (i >= nEntries) return;
    v2f v = __builtin_nontemporal_load(&tables[i]);
    tab16[i] = (bf16_rne(v.x) << 16) | bf16_rne(v.y);
}

// ---------------------------------------------------------------------------
// Fused kernel: one thread = one point, ALL 16 levels, final layout written
// directly. Eliminates the 384 MB stage+transpose pass (was ~200 us of the
// 547 us graph) and the 16x xyz re-read.
//
// Why this preserves table L2-residency (the reason level-partitioning
// existed): every block executes the SAME level sequence (15 -> 0, fully
// unrolled), so at any wall-clock instant the resident waves on an XCD span
// ~1-2 adjacent levels; the XCD's 4 MiB L2 holds the hot 2 MiB table just
// like the level-partitioned schedule did -- and the work is now perfectly
// XCD-balanced by construction (R1's best schedule still had 1.3x skew).
// Phase drift is backstopped by L3 (all 32 MiB of tab16 stays L3-resident).
//
// Rounds 2-4 established the gather path itself is at its structural floor:
// fewer requests (R2) = neutral, more MLP (R3) = worse, fewer lines via
// dense cells (R4) = worse (footprint blowup thrashed L2). So we stop
// touching the gathers and remove the other half of the graph instead.
//
// rx[]/ry[] are indexed only by compile-time constants after full unroll
// (rule #20: no runtime-indexed register arrays). __launch_bounds__(256,4)
// caps VGPR at 128 (32-float accumulator + working set fits; 16 waves/CU).
__global__ __launch_bounds__(256, 4) void hashgrid_fused_kernel(
    const float* __restrict__ xyz,
    const uint32_t* __restrict__ tab16,
    v4f* __restrict__ out4,
    LevelParams lp)
{
    unsigned int n = blockIdx.x * 256u + threadIdx.x;

    float x = xyz[n * 3 + 0];
    float y = xyz[n * 3 + 1];
    float z = xyz[n * 3 + 2];

    float rx[NLEVELS], ry[NLEVELS];

#pragma unroll
    for (int li = 0; li < NLEVELS; ++li) {
        const int l = NLEVELS - 1 - li;          // fine-first while in phase
        float cell = lp.cell[l];

        // floor(x / cell) with IEEE-correct f32 division (matches reference)
        float fx = floorf(x / cell);
        float fy = floorf(y / cell);
        float fz = floorf(z / cell);

        float mvx = fx * cell, mvy = fy * cell, mvz = fz * cell;
        float dnx = (mvx + cell) - mvx;
        float dny = (mvy + cell) - mvy;
        float dnz = (mvz + cell) - mvz;

        float dx = (x - mvx) * __builtin_amdgcn_rcpf(dnx);
        float dy = (y - mvy) * __builtin_amdgcn_rcpf(dny);
        float dz = (z - mvz) * __builtin_amdgcn_rcpf(dnz);

        unsigned int ix = (unsigned int)(int)fx;
        unsigned int iy = (unsigned int)(int)fy;
        unsigned int iz = (unsigned int)(int)fz;

        unsigned int hx0 = ix,      hx1 = ix + 1u;
        unsigned int hy0 = iy * P1, hy1 = hy0 + P1;
        unsigned int hz0 = iz * P2, hz1 = hz0 + P2;

        const uint32_t* __restrict__ tab = tab16 + (size_t)l * TSIZE;

        uint32_t u0 = tab[(hx0 ^ hy0 ^ hz0) & HMASK];
        uint32_t u1 = tab[(hx0 ^ hy0 ^ hz1) & HMASK];
        uint32_t u2 = tab[(hx0 ^ hy1 ^ hz0) & HMASK];
        uint32_t u3 = tab[(hx0 ^ hy1 ^ hz1) & HMASK];
        uint32_t u4 = tab[(hx1 ^ hy0 ^ hz0) & HMASK];
        uint32_t u5 = tab[(hx1 ^ hy0 ^ hz1) & HMASK];
        uint32_t u6 = tab[(hx1 ^ hy1 ^ hz0) & HMASK];
        uint32_t u7 = tab[(hx1 ^ hy1 ^ hz1) & HMASK];

        #define UX(u) __uint_as_float((u) & 0xFFFF0000u)
        #define UY(u) __uint_as_float((u) << 16)

        float wx0 = 1.0f - dx, wy0 = 1.0f - dy, wz0 = 1.0f - dz;

        float c00x = UX(u0) * wx0 + UX(u4) * dx;
        float c00y = UY(u0) * wx0 + UY(u4) * dx;
        float c01x = UX(u1) * wx0 + UX(u5) * dx;
        float c01y = UY(u1) * wx0 + UY(u5) * dx;
        float c10x = UX(u2) * wx0 + UX(u6) * dx;
        float c10y = UY(u2) * wx0 + UY(u6) * dx;
        float c11x = UX(u3) * wx0 + UX(u7) * dx;
        float c11y = UY(u3) * wx0 + UY(u7) * dx;

        #undef UX
        #undef UY

        float c0x = c00x * wy0 + c10x * dy;
        float c0y = c00y * wy0 + c10y * dy;
        float c1x = c01x * wy0 + c11x * dy;
        float c1y = c01y * wy0 + c11y * dy;

        rx[l] = c0x * wz0 + c1x * dz;
        ry[l] = c0y * wz0 + c1y * dz;
    }

    // Write the full 128B record: 4 x dwordx4, lines fully covered by the
    // wave's 8 consecutive store instructions -> full-line nt streaming.
#pragma unroll
    for (int k = 0; k < 8; ++k) {
        v4f w;
        w.x = rx[2 * k];     w.y = ry[2 * k];
        w.z = rx[2 * k + 1]; w.w = ry[2 * k + 1];
        __builtin_nontemporal_store(w, &out4[(size_t)n * 8u + (unsigned)k]);
    }
}

// ---------------------------------------------------------------------------
// Fallback: direct f32 gathers, used only if ws is too small.
__global__ __launch_bounds__(256) void hashgrid_direct_kernel(
    const float* __restrict__ xyz,
    const float* __restrict__ tables,
    float2* __restrict__ out,
    LevelParams lp,
    unsigned int total)
{
    unsigned int t = blockIdx.x * 256u + threadIdx.x;
    if (t >= total) return;
    unsigned int n = t >> 4;
    unsigned int l = t & 15u;

    float x = xyz[n * 3 + 0], y = xyz[n * 3 + 1], z = xyz[n * 3 + 2];
    float cell = lp.cell[l];
    float fx = floorf(x / cell), fy = floorf(y / cell), fz = floorf(z / cell);
    float mvx = fx * cell, mvy = fy * cell, mvz = fz * cell;
    float dnx = (mvx + cell) - mvx, dny = (mvy + cell) - mvy, dnz = (mvz + cell) - mvz;
    float dx = (x - mvx) * __builtin_amdgcn_rcpf(dnx);
    float dy = (y - mvy) * __builtin_amdgcn_rcpf(dny);
    float dz = (z - mvz) * __builtin_amdgcn_rcpf(dnz);
    unsigned int ix = (unsigned int)(int)fx, iy = (unsigned int)(int)fy, iz = (unsigned int)(int)fz;
    unsigned int hx0 = ix, hx1 = ix + 1u;
    unsigned int hy0 = iy * P1, hy1 = hy0 + P1;
    unsigned int hz0 = iz * P2, hz1 = hz0 + P2;
    const float2* __restrict__ tab = (const float2*)tables + (size_t)l * TSIZE;
    float2 e0 = tab[(hx0 ^ hy0 ^ hz0) & HMASK];
    float2 e1 = tab[(hx0 ^ hy0 ^ hz1) & HMASK];
    float2 e2 = tab[(hx0 ^ hy1 ^ hz0) & HMASK];
    float2 e3 = tab[(hx0 ^ hy1 ^ hz1) & HMASK];
    float2 e4 = tab[(hx1 ^ hy0 ^ hz0) & HMASK];
    float2 e5 = tab[(hx1 ^ hy0 ^ hz1) & HMASK];
    float2 e6 = tab[(hx1 ^ hy1 ^ hz0) & HMASK];
    float2 e7 = tab[(hx1 ^ hy1 ^ hz1) & HMASK];
    float wx0 = 1.0f - dx, wy0 = 1.0f - dy, wz0 = 1.0f - dz;
    float c00x = e0.x * wx0 + e4.x * dx, c00y = e0.y * wx0 + e4.y * dx;
    float c01x = e1.x * wx0 + e5.x * dx, c01y = e1.y * wx0 + e5.y * dx;
    float c10x = e2.x * wx0 + e6.x * dx, c10y = e2.y * wx0 + e6.y * dx;
    float c11x = e3.x * wx0 + e7.x * dx, c11y = e3.y * wx0 + e7.y * dx;
    float c0x = c00x * wy0 + c10x * dy, c0y = c00y * wy0 + c10y * dy;
    float c1x = c01x * wy0 + c11x * dy, c1y = c01y * wy0 + c11y * dy;
    out[t] = make_float2(c0x * wz0 + c1x * dz, c0y * wz0 + c1y * dz);
}

// ---------------------------------------------------------------------------
extern "C" void kernel_launch(void* const* d_in, const int* in_sizes, int n_in,
                              void* d_out, int out_size, void* d_ws, size_t ws_size,
                              hipStream_t stream)
{
    const float* xyz    = (const float*)d_in[0];
    const float* tables = (const float*)d_in[1];

    // Resolutions via the SAME libm calls CPython makes (bit-exact floors).
    LevelParams lp;
    double bg = exp((log(512.0) - log(16.0)) / 15.0);
    for (int i = 0; i < NLEVELS; ++i) {
        int res = (int)floor(16.0 * pow(bg, (double)i));
        lp.cell[i] = 1.0f / (float)res;
    }

    unsigned int npts = (unsigned int)(in_sizes[0] / 3);
    size_t tabBytes = (size_t)NLEVELS * TSIZE * 4u;   // 32 MiB

    if (ws_size >= tabBytes && (npts & 255u) == 0u) {
        uint32_t* tab16 = (uint32_t*)d_ws;

        unsigned int nEntries = NLEVELS * TSIZE;
        hipLaunchKernelGGL(convert_tables_kernel,
                           dim3(nEntries / 256u), dim3(256), 0, stream,
                           (const v2f*)tables, tab16, nEntries);

        hipLaunchKernelGGL(hashgrid_fused_kernel,
                           dim3(npts / 256u), dim3(256), 0, stream,
                           xyz, tab16, (v4f*)d_out, lp);
    } else {
        unsigned int total = npts * (unsigned int)NLEVELS;
        hipLaunchKernelGGL(hashgrid_direct_kernel,
                           dim3((total + 255u) / 256u), dim3(256), 0, stream,
                           xyz, tables, (float2*)d_out, lp, total);
    }
}

// Round 7
// 595.048 us; speedup vs baseline: 1.2082x; 1.2082x over previous
//
#include <hip/hip_runtime.h>
#include <math.h>
#include <stdint.h>

#define NLEVELS 16
#define TSIZE   (1u << 19)
#define HMASK   (TSIZE - 1u)
#define P1 2654435761u
#define P2 805459861u

typedef float v2f __attribute__((ext_vector_type(2)));
typedef float v4f __attribute__((ext_vector_type(4)));

// Per-XCD secondary-stream schedule: up to 4 (level, count, base) segments
// covering the SECOND phase (j >= chunks). First phase is level 8+xcd.
struct LevelParams {
    float    cell[NLEVELS];
    uint32_t slvl[8][4];
    uint32_t scnt[8][4];
    uint32_t sbase[8][4];
};

__device__ __forceinline__ uint32_t bf16_rne(float f) {
    uint32_t b = __float_as_uint(f);
    return (b + 0x7FFFu + ((b >> 16) & 1u)) >> 16;   // round-to-nearest-even
}

// ---------------------------------------------------------------------------
// Phase 0: f32 tables -> packed bf16x2 (4 B/entry) in ws (rebuilt every call).
__global__ __launch_bounds__(256) void convert_tables_kernel(
    const v2f* __restrict__ tables, uint32_t* __restrict__ tab16,
    unsigned int nEntries)
{
    unsigned int i = blockIdx.x * 256u + threadIdx.x;
    if (i >= nEntries) return;
    v2f v = __builtin_nontemporal_load(&tables[i]);
    tab16[i] = (bf16_rne(v.x) << 16) | bf16_rne(v.y);
}

// ---------------------------------------------------------------------------
// Phase 1: compute, level-partitioned across XCDs (blockIdx%8 -> XCD).
//
// Round-6 structure: SEQUENTIAL per-XCD phases instead of the j&1 interleave.
//   phase A (j < chunks):   fine level 8+xcd -- the XCD's L2 holds exactly
//                           one 2 MiB table, exclusively.
//   phase B (j >= chunks):  secondary stream (l7 quarters on X0-3, l6 halves
//                           on X4-5, l5/l4 split on X6-7, tinies as filler)
//                           -- again at most one heavy table resident.
// R1's interleave co-scheduled fine+l7 = 4 MiB on X0-3 -> thrash (FETCH grew
// 67->100 MB). The line-service model says the L2 only cares which lines it
// must hold, not which waves issue -- so dedicating the L2 to one table per
// phase removes the refetch without losing anything. Dispatch is
// blockIdx-ordered, so the phase boundary mixes only ~3% of blocks.
//
// xyz loads are NONTEMPORAL: 12 MB/level-pass of streaming reads otherwise
// continuously evict table lines from L2 (they are L3-served re-reads; no
// reuse within a pass).
__global__ __launch_bounds__(256) void hashgrid_compute_kernel(
    const float* __restrict__ xyz,
    const uint32_t* __restrict__ tab16,
    v2f* __restrict__ stage,
    LevelParams lp,
    unsigned int npts,
    unsigned int chunks)
{
    unsigned int b   = blockIdx.x;
    unsigned int xcd = b & 7u;
    unsigned int j   = b >> 3;

    unsigned int level, chunk;
    if (j >= chunks) {                   // phase B: secondary stream
        unsigned int t = j - chunks;
        unsigned int s = 0;
        while (s < 3u && t >= lp.scnt[xcd][s]) { t -= lp.scnt[xcd][s]; ++s; }
        level = lp.slvl[xcd][s];
        chunk = lp.sbase[xcd][s] + t;
    } else {                             // phase A: fine level, L2-exclusive
        level = 8u + xcd;
        chunk = j;
    }
    unsigned int n = chunk * 256u + threadIdx.x;

    float x = __builtin_nontemporal_load(&xyz[n * 3 + 0]);
    float y = __builtin_nontemporal_load(&xyz[n * 3 + 1]);
    float z = __builtin_nontemporal_load(&xyz[n * 3 + 2]);

    float cell = lp.cell[level];   // block-uniform

    // floor(x / cell) with IEEE-correct f32 division (matches reference)
    float fx = floorf(x / cell);
    float fy = floorf(y / cell);
    float fz = floorf(z / cell);

    float mvx = fx * cell, mvy = fy * cell, mvz = fz * cell;
    float dnx = (mvx + cell) - mvx;
    float dny = (mvy + cell) - mvy;
    float dnz = (mvz + cell) - mvz;

    float dx = (x - mvx) * __builtin_amdgcn_rcpf(dnx);
    float dy = (y - mvy) * __builtin_amdgcn_rcpf(dny);
    float dz = (z - mvz) * __builtin_amdgcn_rcpf(dnz);

    unsigned int ix = (unsigned int)(int)fx;
    unsigned int iy = (unsigned int)(int)fy;
    unsigned int iz = (unsigned int)(int)fz;

    unsigned int hx0 = ix,      hx1 = ix + 1u;
    unsigned int hy0 = iy * P1, hy1 = hy0 + P1;
    unsigned int hz0 = iz * P2, hz1 = hz0 + P2;

    const uint32_t* __restrict__ tab = tab16 + (size_t)level * TSIZE;

    uint32_t u0 = tab[(hx0 ^ hy0 ^ hz0) & HMASK];
    uint32_t u1 = tab[(hx0 ^ hy0 ^ hz1) & HMASK];
    uint32_t u2 = tab[(hx0 ^ hy1 ^ hz0) & HMASK];
    uint32_t u3 = tab[(hx0 ^ hy1 ^ hz1) & HMASK];
    uint32_t u4 = tab[(hx1 ^ hy0 ^ hz0) & HMASK];
    uint32_t u5 = tab[(hx1 ^ hy0 ^ hz1) & HMASK];
    uint32_t u6 = tab[(hx1 ^ hy1 ^ hz0) & HMASK];
    uint32_t u7 = tab[(hx1 ^ hy1 ^ hz1) & HMASK];

    #define UX(u) __uint_as_float((u) & 0xFFFF0000u)
    #define UY(u) __uint_as_float((u) << 16)

    float wx0 = 1.0f - dx, wy0 = 1.0f - dy, wz0 = 1.0f - dz;

    float c00x = UX(u0) * wx0 + UX(u4) * dx;
    float c00y = UY(u0) * wx0 + UY(u4) * dx;
    float c01x = UX(u1) * wx0 + UX(u5) * dx;
    float c01y = UY(u1) * wx0 + UY(u5) * dx;
    float c10x = UX(u2) * wx0 + UX(u6) * dx;
    float c10y = UY(u2) * wx0 + UY(u6) * dx;
    float c11x = UX(u3) * wx0 + UX(u7) * dx;
    float c11y = UY(u3) * wx0 + UY(u7) * dx;

    #undef UX
    #undef UY

    float c0x = c00x * wy0 + c10x * dy;
    float c0y = c00y * wy0 + c10y * dy;
    float c1x = c01x * wy0 + c11x * dy;
    float c1y = c01y * wy0 + c11y * dy;

    v2f r;
    r.x = c0x * wz0 + c1x * dz;
    r.y = c0y * wz0 + c1y * dz;

    __builtin_nontemporal_store(r, &stage[(size_t)level * npts + n]);
}

// ---------------------------------------------------------------------------
// Phase 2: transpose stage[l][n] -> out[n][l] via LDS.
// Loads: 16 coalesced level-major rows. LDS [256][17] float2 (pad 17 breaks
// the stride-16 bank pattern; write aliasing is 2-way = free). Stores: flat
// index blk*2048 + iter*256 + tid -> 1 KiB contiguous per wave instruction
// (16 full lines) so nt streaming stores are full-line and safe.
__global__ __launch_bounds__(256) void transpose_kernel(
    const v2f* __restrict__ stage, v4f* __restrict__ out4, unsigned int npts)
{
    __shared__ v2f lds[256][17];
    unsigned int tid  = threadIdx.x;
    unsigned int base = blockIdx.x * 256u;

#pragma unroll
    for (int l = 0; l < NLEVELS; ++l)
        lds[tid][l] = __builtin_nontemporal_load(&stage[(size_t)l * npts + base + tid]);

    __syncthreads();

#pragma unroll
    for (int it = 0; it < 8; ++it) {
        unsigned int i = it * 256u + tid;        // 0..2047 within block
        unsigned int p = i >> 3;                 // point within block
        unsigned int k = i & 7u;                 // float4 index within record
        v2f a = lds[p][2 * k];
        v2f c = lds[p][2 * k + 1];
        v4f w; w.x = a.x; w.y = a.y; w.z = c.x; w.w = c.y;
        __builtin_nontemporal_store(w, &out4[(size_t)blockIdx.x * 2048u + i]);
    }
}

// ---------------------------------------------------------------------------
// Fallback: direct f32 gathers, used only if ws is too small.
__global__ __launch_bounds__(256) void hashgrid_direct_kernel(
    const float* __restrict__ xyz,
    const float* __restrict__ tables,
    float2* __restrict__ out,
    LevelParams lp,
    unsigned int total)
{
    unsigned int t = blockIdx.x * 256u + threadIdx.x;
    if (t >= total) return;
    unsigned int n = t >> 4;
    unsigned int l = t & 15u;

    float x = xyz[n * 3 + 0], y = xyz[n * 3 + 1], z = xyz[n * 3 + 2];
    float cell = lp.cell[l];
    float fx = floorf(x / cell), fy = floorf(y / cell), fz = floorf(z / cell);
    float mvx = fx * cell, mvy = fy * cell, mvz = fz * cell;
    float dnx = (mvx + cell) - mvx, dny = (mvy + cell) - mvy, dnz = (mvz + cell) - mvz;
    float dx = (x - mvx) * __builtin_amdgcn_rcpf(dnx);
    float dy = (y - mvy) * __builtin_amdgcn_rcpf(dny);
    float dz = (z - mvz) * __builtin_amdgcn_rcpf(dnz);
    unsigned int ix = (unsigned int)(int)fx, iy = (unsigned int)(int)fy, iz = (unsigned int)(int)fz;
    unsigned int hx0 = ix, hx1 = ix + 1u;
    unsigned int hy0 = iy * P1, hy1 = hy0 + P1;
    unsigned int hz0 = iz * P2, hz1 = hz0 + P2;
    const float2* __restrict__ tab = (const float2*)tables + (size_t)l * TSIZE;
    float2 e0 = tab[(hx0 ^ hy0 ^ hz0) & HMASK];
    float2 e1 = tab[(hx0 ^ hy0 ^ hz1) & HMASK];
    float2 e2 = tab[(hx0 ^ hy1 ^ hz0) & HMASK];
    float2 e3 = tab[(hx0 ^ hy1 ^ hz1) & HMASK];
    float2 e4 = tab[(hx1 ^ hy0 ^ hz0) & HMASK];
    float2 e5 = tab[(hx1 ^ hy0 ^ hz1) & HMASK];
    float2 e6 = tab[(hx1 ^ hy1 ^ hz0) & HMASK];
    float2 e7 = tab[(hx1 ^ hy1 ^ hz1) & HMASK];
    float wx0 = 1.0f - dx, wy0 = 1.0f - dy, wz0 = 1.0f - dz;
    float c00x = e0.x * wx0 + e4.x * dx, c00y = e0.y * wx0 + e4.y * dx;
    float c01x = e1.x * wx0 + e5.x * dx, c01y = e1.y * wx0 + e5.y * dx;
    float c10x = e2.x * wx0 + e6.x * dx, c10y = e2.y * wx0 + e6.y * dx;
    float c11x = e3.x * wx0 + e7.x * dx, c11y = e3.y * wx0 + e7.y * dx;
    float c0x = c00x * wy0 + c10x * dy, c0y = c00y * wy0 + c10y * dy;
    float c1x = c01x * wy0 + c11x * dy, c1y = c01y * wy0 + c11y * dy;
    out[t] = make_float2(c0x * wz0 + c1x * dz, c0y * wz0 + c1y * dz);
}

// ---------------------------------------------------------------------------
extern "C" void kernel_launch(void* const* d_in, const int* in_sizes, int n_in,
                              void* d_out, int out_size, void* d_ws, size_t ws_size,
                              hipStream_t stream)
{
    const float* xyz    = (const float*)d_in[0];
    const float* tables = (const float*)d_in[1];

    // Resolutions via the SAME libm calls CPython makes (bit-exact floors).
    LevelParams lp;
    double bg = exp((log(512.0) - log(16.0)) / 15.0);
    for (int i = 0; i < NLEVELS; ++i) {
        int res = (int)floor(16.0 * pow(bg, (double)i));
        lp.cell[i] = 1.0f / (float)res;
    }

    unsigned int npts = (unsigned int)(in_sizes[0] / 3);
    size_t tabBytes   = (size_t)NLEVELS * TSIZE * 4u;         // 32 MiB
    size_t stageBytes = (size_t)npts * NLEVELS * sizeof(v2f); // 128 MiB

    if (ws_size >= tabBytes + stageBytes && (npts & 255u) == 0u) {
        uint32_t* tab16 = (uint32_t*)d_ws;
        v2f* stage = (v2f*)((char*)d_ws + tabBytes);

        unsigned int nEntries = NLEVELS * TSIZE;
        hipLaunchKernelGGL(convert_tables_kernel,
                           dim3(nEntries / 256u), dim3(256), 0, stream,
                           (const v2f*)tables, tab16, nEntries);

        unsigned int chunks = npts / 256u;                  // 4096 for 2^20 pts

        // Phase-B (secondary) schedule. Per-XCD block counts must equal
        // `chunks`. Weights (line-work, rel. to a full-table level):
        // l7=1.0 l6=.52 l5=.27 l4=.14 l3=.07 l2=.035 l1=.019 l0=.01.
        for (int x = 0; x < 8; ++x)
            for (int s = 0; s < 4; ++s) {
                lp.slvl[x][s] = 0; lp.scnt[x][s] = 0; lp.sbase[x][s] = 0;
            }
        if ((chunks & 3u) == 0u) {
            unsigned int q = chunks / 4u;
            // X0-3: l7 quarter (2 MiB, L2-exclusive in phase B) + tiny filler.
            for (unsigned x = 0; x < 4; ++x) {
                lp.slvl[x][0] = 7; lp.scnt[x][0] = q;      lp.sbase[x][0] = x * q;
                lp.slvl[x][1] = x; lp.scnt[x][1] = 3u * q; lp.sbase[x][1] = 0;
            }
            // X4: l6 first half + tails of l0,l1.
            lp.slvl[4][0] = 6; lp.scnt[4][0] = 2u * q; lp.sbase[4][0] = 0;
            lp.slvl[4][1] = 0; lp.scnt[4][1] = q;      lp.sbase[4][1] = 3u * q;
            lp.slvl[4][2] = 1; lp.scnt[4][2] = q;      lp.sbase[4][2] = 3u * q;
            // X5: l6 second half + tails of l2,l3.
            lp.slvl[5][0] = 6; lp.scnt[5][0] = 2u * q; lp.sbase[5][0] = 2u * q;
            lp.slvl[5][1] = 2; lp.scnt[5][1] = q;      lp.sbase[5][1] = 3u * q;
            lp.slvl[5][2] = 3; lp.scnt[5][2] = q;      lp.sbase[5][2] = 3u * q;
            // X6: l5 x 3q + l4 tail (weight .235); X7: l4 x 3q + l5 tail (.172)
            lp.slvl[6][0] = 5; lp.scnt[6][0] = 3u * q; lp.sbase[6][0] = 0;
            lp.slvl[6][1] = 4; lp.scnt[6][1] = q;      lp.sbase[6][1] = 3u * q;
            lp.slvl[7][0] = 4; lp.scnt[7][0] = 3u * q; lp.sbase[7][0] = 0;
            lp.slvl[7][1] = 5; lp.scnt[7][1] = q;      lp.sbase[7][1] = 3u * q;
        } else {
            // Generic fallback schedule: xcd -> secondary level xcd (0..7).
            for (int x = 0; x < 8; ++x) {
                lp.slvl[x][0] = (unsigned)x; lp.scnt[x][0] = chunks; lp.sbase[x][0] = 0;
            }
        }

        hipLaunchKernelGGL(hashgrid_compute_kernel,
                           dim3(NLEVELS * chunks), dim3(256), 0, stream,
                           xyz, tab16, stage, lp, npts, chunks);

        hipLaunchKernelGGL(transpose_kernel,
                           dim3(npts / 256u), dim3(256), 0, stream,
                           stage, (v4f*)d_out, npts);
    } else {
        unsigned int total = npts * (unsigned int)NLEVELS;
        hipLaunchKernelGGL(hashgrid_direct_kernel,
                           dim3((total + 255u) / 256u), dim3(256), 0, stream,
                           xyz, tables, (float2*)d_out, lp, total);
    }
}

// Round 8
// 541.561 us; speedup vs baseline: 1.3275x; 1.0988x over previous
//
#include <hip/hip_runtime.h>
#include <math.h>
#include <stdint.h>

#define NLEVELS 16
#define TSIZE   (1u << 19)
#define HMASK   (TSIZE - 1u)
#define P1 2654435761u
#define P2 805459861u

typedef float v2f __attribute__((ext_vector_type(2)));
typedef float v4f __attribute__((ext_vector_type(4)));

// Per-XCD secondary-stream schedule: up to 3 (level, count, base) segments
// covering the odd-j block slots. Even-j slots are always level 8+xcd.
struct LevelParams {
    float    cell[NLEVELS];
    uint32_t slvl[8][3];
    uint32_t scnt[8][3];
    uint32_t sbase[8][3];
};

__device__ __forceinline__ uint32_t bf16_rne(float f) {
    uint32_t b = __float_as_uint(f);
    return (b + 0x7FFFu + ((b >> 16) & 1u)) >> 16;   // round-to-nearest-even
}

// ---------------------------------------------------------------------------
// Phase 0: f32 tables -> packed bf16x2 (4 B/entry) in ws (rebuilt every call).
__global__ __launch_bounds__(256) void convert_tables_kernel(
    const v2f* __restrict__ tables, uint32_t* __restrict__ tab16,
    unsigned int nEntries)
{
    unsigned int i = blockIdx.x * 256u + threadIdx.x;
    if (i >= nEntries) return;
    v2f v = __builtin_nontemporal_load(&tables[i]);
    tab16[i] = (bf16_rne(v.x) << 16) | bf16_rne(v.y);
}

// ---------------------------------------------------------------------------
// Phase 1: compute, level-partitioned across XCDs (blockIdx%8 -> XCD).
// Even j: XCD k runs fine level 8+k. Odd j: a per-XCD "secondary" stream,
// scheduled so the per-XCD L2-line work is balanced:
//   XCD0..3: 1/4 of l7 (each caches whole l7 table) + l0..l3
//   XCD4:    1/2 of l6 + tails of l0,l1
//   XCD5:    1/2 of l6 + tails of l2,l3
//   XCD6:    l5
//   XCD7:    l4
// Max per-XCD line weight ~1.30 vs 2.0 for the naive pairing.
//
// FINAL-FORM NOTE (rounds 2-7 evidence): this kernel is bound by L2
// random-line service (~11 lines/cy/XCD vs 16-channel ideal; random-address
// channel collisions account for the gap). Probed and rejected:
//   R2 fewer scattered requests (quad-merge)      -> neutral
//   R3 2x per-wave MLP (2 pts/thread)             -> -11%
//   R4 dense cell tables (1 line/pt)              -> -34% (footprint thrash)
//   R5 full fusion, no stage/transpose            -> -31% (phase drift, 1.4GB)
//   R7 sequential phases + nt xyz (anti-pollution)-> -17% (interleave is load-
//      diversity, not pollution; HBM refetch is only ~2% of gathers)
// The j&1 interleave + this balance IS the optimum found.
__global__ __launch_bounds__(256) void hashgrid_compute_kernel(
    const float* __restrict__ xyz,
    const uint32_t* __restrict__ tab16,
    v2f* __restrict__ stage,
    LevelParams lp,
    unsigned int npts)
{
    unsigned int b   = blockIdx.x;
    unsigned int xcd = b & 7u;
    unsigned int j   = b >> 3;

    unsigned int level, chunk;
    if (j & 1u) {
        unsigned int t = j >> 1;
        unsigned int s = 0;
        while (s < 2u && t >= lp.scnt[xcd][s]) { t -= lp.scnt[xcd][s]; ++s; }
        level = lp.slvl[xcd][s];
        chunk = lp.sbase[xcd][s] + t;
    } else {
        level = 8u + xcd;
        chunk = j >> 1;
    }
    unsigned int n = chunk * 256u + threadIdx.x;

    float x = xyz[n * 3 + 0];
    float y = xyz[n * 3 + 1];
    float z = xyz[n * 3 + 2];

    float cell = lp.cell[level];   // block-uniform

    // floor(x / cell) with IEEE-correct f32 division (matches reference)
    float fx = floorf(x / cell);
    float fy = floorf(y / cell);
    float fz = floorf(z / cell);

    float mvx = fx * cell, mvy = fy * cell, mvz = fz * cell;
    float dnx = (mvx + cell) - mvx;
    float dny = (mvy + cell) - mvy;
    float dnz = (mvz + cell) - mvz;

    float dx = (x - mvx) * __builtin_amdgcn_rcpf(dnx);
    float dy = (y - mvy) * __builtin_amdgcn_rcpf(dny);
    float dz = (z - mvz) * __builtin_amdgcn_rcpf(dnz);

    unsigned int ix = (unsigned int)(int)fx;
    unsigned int iy = (unsigned int)(int)fy;
    unsigned int iz = (unsigned int)(int)fz;

    unsigned int hx0 = ix,      hx1 = ix + 1u;
    unsigned int hy0 = iy * P1, hy1 = hy0 + P1;
    unsigned int hz0 = iz * P2, hz1 = hz0 + P2;

    const uint32_t* __restrict__ tab = tab16 + (size_t)level * TSIZE;

    uint32_t u0 = tab[(hx0 ^ hy0 ^ hz0) & HMASK];
    uint32_t u1 = tab[(hx0 ^ hy0 ^ hz1) & HMASK];
    uint32_t u2 = tab[(hx0 ^ hy1 ^ hz0) & HMASK];
    uint32_t u3 = tab[(hx0 ^ hy1 ^ hz1) & HMASK];
    uint32_t u4 = tab[(hx1 ^ hy0 ^ hz0) & HMASK];
    uint32_t u5 = tab[(hx1 ^ hy0 ^ hz1) & HMASK];
    uint32_t u6 = tab[(hx1 ^ hy1 ^ hz0) & HMASK];
    uint32_t u7 = tab[(hx1 ^ hy1 ^ hz1) & HMASK];

    #define UX(u) __uint_as_float((u) & 0xFFFF0000u)
    #define UY(u) __uint_as_float((u) << 16)

    float wx0 = 1.0f - dx, wy0 = 1.0f - dy, wz0 = 1.0f - dz;

    float c00x = UX(u0) * wx0 + UX(u4) * dx;
    float c00y = UY(u0) * wx0 + UY(u4) * dx;
    float c01x = UX(u1) * wx0 + UX(u5) * dx;
    float c01y = UY(u1) * wx0 + UY(u5) * dx;
    float c10x = UX(u2) * wx0 + UX(u6) * dx;
    float c10y = UY(u2) * wx0 + UY(u6) * dx;
    float c11x = UX(u3) * wx0 + UX(u7) * dx;
    float c11y = UY(u3) * wx0 + UY(u7) * dx;

    #undef UX
    #undef UY

    float c0x = c00x * wy0 + c10x * dy;
    float c0y = c00y * wy0 + c10y * dy;
    float c1x = c01x * wy0 + c11x * dy;
    float c1y = c01y * wy0 + c11y * dy;

    v2f r;
    r.x = c0x * wz0 + c1x * dz;
    r.y = c0y * wz0 + c1y * dz;

    __builtin_nontemporal_store(r, &stage[(size_t)level * npts + n]);
}

// ---------------------------------------------------------------------------
// Phase 2: transpose stage[l][n] -> out[n][l] via LDS.
// Loads: 16 coalesced level-major rows. LDS [256][17] float2 (pad 17 breaks
// the stride-16 bank pattern; write aliasing is 2-way = free). Stores: flat
// index blk*2048 + iter*256 + tid -> 1 KiB contiguous per wave instruction
// (16 full lines) so nt streaming stores are full-line and safe.
__global__ __launch_bounds__(256) void transpose_kernel(
    const v2f* __restrict__ stage, v4f* __restrict__ out4, unsigned int npts)
{
    __shared__ v2f lds[256][17];
    unsigned int tid  = threadIdx.x;
    unsigned int base = blockIdx.x * 256u;

#pragma unroll
    for (int l = 0; l < NLEVELS; ++l)
        lds[tid][l] = __builtin_nontemporal_load(&stage[(size_t)l * npts + base + tid]);

    __syncthreads();

#pragma unroll
    for (int it = 0; it < 8; ++it) {
        unsigned int i = it * 256u + tid;        // 0..2047 within block
        unsigned int p = i >> 3;                 // point within block
        unsigned int k = i & 7u;                 // float4 index within record
        v2f a = lds[p][2 * k];
        v2f c = lds[p][2 * k + 1];
        v4f w; w.x = a.x; w.y = a.y; w.z = c.x; w.w = c.y;
        __builtin_nontemporal_store(w, &out4[(size_t)blockIdx.x * 2048u + i]);
    }
}

// ---------------------------------------------------------------------------
// Fallback: direct f32 gathers, used only if ws is too small.
__global__ __launch_bounds__(256) void hashgrid_direct_kernel(
    const float* __restrict__ xyz,
    const float* __restrict__ tables,
    float2* __restrict__ out,
    LevelParams lp,
    unsigned int total)
{
    unsigned int t = blockIdx.x * 256u + threadIdx.x;
    if (t >= total) return;
    unsigned int n = t >> 4;
    unsigned int l = t & 15u;

    float x = xyz[n * 3 + 0], y = xyz[n * 3 + 1], z = xyz[n * 3 + 2];
    float cell = lp.cell[l];
    float fx = floorf(x / cell), fy = floorf(y / cell), fz = floorf(z / cell);
    float mvx = fx * cell, mvy = fy * cell, mvz = fz * cell;
    float dnx = (mvx + cell) - mvx, dny = (mvy + cell) - mvy, dnz = (mvz + cell) - mvz;
    float dx = (x - mvx) * __builtin_amdgcn_rcpf(dnx);
    float dy = (y - mvy) * __builtin_amdgcn_rcpf(dny);
    float dz = (z - mvz) * __builtin_amdgcn_rcpf(dnz);
    unsigned int ix = (unsigned int)(int)fx, iy = (unsigned int)(int)fy, iz = (unsigned int)(int)fz;
    unsigned int hx0 = ix, hx1 = ix + 1u;
    unsigned int hy0 = iy * P1, hy1 = hy0 + P1;
    unsigned int hz0 = iz * P2, hz1 = hz0 + P2;
    const float2* __restrict__ tab = (const float2*)tables + (size_t)l * TSIZE;
    float2 e0 = tab[(hx0 ^ hy0 ^ hz0) & HMASK];
    float2 e1 = tab[(hx0 ^ hy0 ^ hz1) & HMASK];
    float2 e2 = tab[(hx0 ^ hy1 ^ hz0) & HMASK];
    float2 e3 = tab[(hx0 ^ hy1 ^ hz1) & HMASK];
    float2 e4 = tab[(hx1 ^ hy0 ^ hz0) & HMASK];
    float2 e5 = tab[(hx1 ^ hy0 ^ hz1) & HMASK];
    float2 e6 = tab[(hx1 ^ hy1 ^ hz0) & HMASK];
    float2 e7 = tab[(hx1 ^ hy1 ^ hz1) & HMASK];
    float wx0 = 1.0f - dx, wy0 = 1.0f - dy, wz0 = 1.0f - dz;
    float c00x = e0.x * wx0 + e4.x * dx, c00y = e0.y * wx0 + e4.y * dx;
    float c01x = e1.x * wx0 + e5.x * dx, c01y = e1.y * wx0 + e5.y * dx;
    float c10x = e2.x * wx0 + e6.x * dx, c10y = e2.y * wx0 + e6.y * dx;
    float c11x = e3.x * wx0 + e7.x * dx, c11y = e3.y * wx0 + e7.y * dx;
    float c0x = c00x * wy0 + c10x * dy, c0y = c00y * wy0 + c10y * dy;
    float c1x = c01x * wy0 + c11x * dy, c1y = c01y * wy0 + c11y * dy;
    out[t] = make_float2(c0x * wz0 + c1x * dz, c0y * wz0 + c1y * dz);
}

// ---------------------------------------------------------------------------
extern "C" void kernel_launch(void* const* d_in, const int* in_sizes, int n_in,
                              void* d_out, int out_size, void* d_ws, size_t ws_size,
                              hipStream_t stream)
{
    const float* xyz    = (const float*)d_in[0];
    const float* tables = (const float*)d_in[1];

    // Resolutions via the SAME libm calls CPython makes (bit-exact floors).
    LevelParams lp;
    double bg = exp((log(512.0) - log(16.0)) / 15.0);
    for (int i = 0; i < NLEVELS; ++i) {
        int res = (int)floor(16.0 * pow(bg, (double)i));
        lp.cell[i] = 1.0f / (float)res;
    }

    unsigned int npts = (unsigned int)(in_sizes[0] / 3);
    size_t tabBytes   = (size_t)NLEVELS * TSIZE * 4u;         // 32 MiB
    size_t stageBytes = (size_t)npts * NLEVELS * sizeof(v2f); // 128 MiB

    if (ws_size >= tabBytes + stageBytes && (npts & 255u) == 0u) {
        uint32_t* tab16 = (uint32_t*)d_ws;
        v2f* stage = (v2f*)((char*)d_ws + tabBytes);

        unsigned int nEntries = NLEVELS * TSIZE;
        hipLaunchKernelGGL(convert_tables_kernel,
                           dim3((nEntries + 255u) / 256u), dim3(256), 0, stream,
                           (const v2f*)tables, tab16, nEntries);

        unsigned int chunks = npts / 256u;                  // 4096

        // Build the secondary (odd-j) schedule, balancing per-XCD L2 work.
        for (int x = 0; x < 8; ++x)
            for (int s = 0; s < 3; ++s) {
                lp.slvl[x][s] = 0; lp.scnt[x][s] = 0; lp.sbase[x][s] = 0;
            }
        if ((chunks & 3u) == 0u) {
            unsigned int q = chunks / 4u;
            // XCD0..3: quarter of l7 + one tiny level (3/4 of it)
            for (int x = 0; x < 4; ++x) {
                lp.slvl[x][0] = 7;         lp.scnt[x][0] = q;      lp.sbase[x][0] = (unsigned)x * q;
                lp.slvl[x][1] = (unsigned)x; lp.scnt[x][1] = 3u * q; lp.sbase[x][1] = 0;
            }
            // XCD4: half of l6 + tails of l0,l1
            lp.slvl[4][0] = 6; lp.scnt[4][0] = 2u * q; lp.sbase[4][0] = 0;
            lp.slvl[4][1] = 0; lp.scnt[4][1] = q;      lp.sbase[4][1] = 3u * q;
            lp.slvl[4][2] = 1; lp.scnt[4][2] = q;      lp.sbase[4][2] = 3u * q;
            // XCD5: half of l6 + tails of l2,l3
            lp.slvl[5][0] = 6; lp.scnt[5][0] = 2u * q; lp.sbase[5][0] = 2u * q;
            lp.slvl[5][1] = 2; lp.scnt[5][1] = q;      lp.sbase[5][1] = 3u * q;
            lp.slvl[5][2] = 3; lp.scnt[5][2] = q;      lp.sbase[5][2] = 3u * q;
            // XCD6: all of l5.  XCD7: all of l4.
            lp.slvl[6][0] = 5; lp.scnt[6][0] = chunks; lp.sbase[6][0] = 0;
            lp.slvl[7][0] = 4; lp.scnt[7][0] = chunks; lp.sbase[7][0] = 0;
        } else {
            // Generic fallback schedule: old pairing (xcd -> coarse level xcd)
            for (int x = 0; x < 8; ++x) {
                lp.slvl[x][0] = (unsigned)x; lp.scnt[x][0] = chunks; lp.sbase[x][0] = 0;
            }
        }

        hipLaunchKernelGGL(hashgrid_compute_kernel,
                           dim3(NLEVELS * chunks), dim3(256), 0, stream,
                           xyz, tab16, stage, lp, npts);

        hipLaunchKernelGGL(transpose_kernel,
                           dim3(chunks), dim3(256), 0, stream,
                           stage, (v4f*)d_out, npts);
    } else {
        unsigned int total = npts * (unsigned int)NLEVELS;
        hipLaunchKernelGGL(hashgrid_direct_kernel,
                           dim3((total + 255u) / 256u), dim3(256), 0, stream,
                           xyz, tables, (float2*)d_out, lp, total);
    }
}